// Round 5
// baseline (109.539 us; speedup 1.0000x reference)
//
#include <hip/hip_runtime.h>
#include <math.h>
#include <utility>

#define BB 64
#define NN 512
#define DD 32
#define ZD 34            // DD + 2 (x..., t, y)
#define NE 595           // ZD*(ZD+1)/2 upper-triangular entries
#define WIN 8
#define NW 64            // NN / WIN windows
#define WACT 60          // active windows w = 4..63 (n <= 31 is rank-deficient -> 0)

// fused gram+scan geometry (entry-per-thread, 128-row segments)
#define SEG 4            // s-segments per batch (128 rows each)
#define RS 128           // rows per segment
#define KWS 16           // windows per segment
#define CH 4             // e-chunks per (b,seg)
#define ECH 149          // entries per chunk (4*149 >= 595)
#define PSTRIDE 17       // 16 exclusive in-segment snapshots + segment total

#define SPW3 3           // solve: systems per wave (3 x 21-lane groups, 2 cols/lane)

// entry e -> (i,j), i <= j, row-major upper triangle of ZD x ZD
__device__ inline void ent2ij(int e, int& i, int& j) {
    int ii = 0, rem = e;
    while (rem >= ZD - ii) { rem -= (ZD - ii); ++ii; }
    i = ii; j = ii + rem;
}

// ---- recursive struct-of-scalars: SROA-guaranteed register residency ----
template<int N> struct Pack { Pack<N - 1> head; float v; };
template<> struct Pack<1> { float v; };
template<int I, int N> __device__ __forceinline__ float& pget(Pack<N>& p) {
    static_assert(I < N, "oob");
    if constexpr (I == N - 1) return p.v;
    else return pget<I, N - 1>(p.head);
}

__device__ __forceinline__ float bperm(int byteaddr, float x) {
    return __int_as_float(__builtin_amdgcn_ds_bpermute(byteaddr, __float_as_int(x)));
}

// Fused window-partial + prefix-scan. Block = (b, s-segment, e-chunk).
// Each thread owns ONE triangle entry e and runs an fp64 prefix chain over the
// segment's 128 rows, emitting the 16 exclusive window snapshots (fp32) plus
// the segment total to P[b][seg][17][NE]. Folds output init: logs[.]=0
// everywhere and means=0 for n < 32.
__global__ __launch_bounds__(256) void dml_gram(const float* __restrict__ xtys,
                                                float* __restrict__ P,
                                                float* __restrict__ out) {
    const int t   = threadIdx.x;
    const int blk = blockIdx.x;                  // ((b*SEG + g)*CH + c)
    const int c   = blk % CH;
    const int bg  = blk / CH;
    const int g   = bg % SEG;
    const int b   = bg / SEG;

    const int gid = blk * 256 + t;
    if (gid < BB * NN) out[BB * NN + gid] = 0.0f;
    if (gid < BB * DD) out[(gid >> 5) * NN + (gid & 31)] = 0.0f;

    __shared__ float zs[RS * ZD];                // 17408 B
    const float* src = xtys + ((size_t)b * NN + (size_t)g * RS) * ZD;
    for (int u = t; u < RS * ZD; u += 256) zs[u] = src[u];
    __syncthreads();

    const int e = c * ECH + t;
    if (t < ECH && e < NE) {
        int i, j;
        ent2ij(e, i, j);
        float* pdst = P + (size_t)(b * SEG + g) * PSTRIDE * NE + e;
        double acc = 0.0;
#pragma unroll
        for (int k = 0; k < KWS; ++k) {
            pdst[k * NE] = (float)acc;           // exclusive: before window k's rows
#pragma unroll
            for (int s8 = 0; s8 < WIN; ++s8) {
                const float* row = &zs[(k * WIN + s8) * ZD];
                acc = fma((double)row[i], (double)row[j], acc);
            }
        }
        pdst[KWS * NE] = (float)acc;             // segment total
    }
}

// ---- solve: THREE systems per wave. Group g = lane/21 (lane 63 idles as a
// clamped duplicate), u = lane - 21g; lane holds columns c0 = u and c1 = u+21
// of its system's symmetric bordered 42x42 matrix [[G0, W],[W^T, 0]],
// W = [x_1..x_8, Xtt0, Xty0]. Broadcasts use ds_bpermute (per-lane crossbar)
// so one instruction serves all 3 groups; each lane updates its 2 columns.
// For K >= 21 all c0 columns are already eliminated (t0 = 0) -> skip pack0.
// Arithmetic is op-for-op identical to the readlane version.

template<int R> __device__ __forceinline__
void init2(Pack<42>& A0, Pack<42>& A1, int c0, int c1, int off0, int off1,
           const float* snW, const float* zbW) {
    if constexpr (R < 42) {
        constexpr int CR = (R < DD) ? (R * ZD - (R * (R - 1)) / 2 - R) : 0;
        float v0, v1;
        if constexpr (R < DD) {
            v0 = snW[(R < c0) ? (CR + c0) : (off0 + R)];
            const float* p1;
            if (c1 < DD)            p1 = &snW[(R < c1) ? (CR + c1) : (off1 + R)];
            else if (c1 < DD + WIN) p1 = &zbW[(c1 - DD) * ZD + R];
            else if (c1 == 40)      p1 = &snW[CR + DD];       // Xtt0[R]
            else                    p1 = &snW[CR + DD + 1];   // Xty0[R] (c1>=41 incl. lane63)
            v1 = *p1;
        } else if constexpr (R < DD + WIN) {
            v0 = zbW[(R - DD) * ZD + c0];
            v1 = (c1 < DD) ? zbW[(R - DD) * ZD + c1] : 0.0f;
        } else if constexpr (R == 40) {
            v0 = snW[off0 + DD];
            v1 = (c1 < DD) ? snW[off1 + DD] : 0.0f;
        } else {
            v0 = snW[off0 + DD + 1];
            v1 = (c1 < DD) ? snW[off1 + DD + 1] : 0.0f;
        }
        pget<R>(A0) = v0;
        pget<R>(A1) = v1;
        init2<R + 1>(A0, A1, c0, c1, off0, off1, snW, zbW);
    }
}

template<int K, int R> __device__ __forceinline__
void elim2_rows(Pack<42>& A0, Pack<42>& A1, float t0, float t1, int gb4) {
    if constexpr (R < 42) {
        float src;
        if constexpr (K < 21) src = pget<R>(A0); else src = pget<R>(A1);
        float fr = bperm(gb4 + 4 * (K < 21 ? K : K - 21), src);  // M[R][K] per group
        if constexpr (K < 21)
            pget<R>(A0) = fmaf(-fr, t0, pget<R>(A0));
        pget<R>(A1) = fmaf(-fr, t1, pget<R>(A1));
        elim2_rows<K, R + 1>(A0, A1, t0, t1, gb4);
    }
}
template<int K> __device__ __forceinline__
void elim2_step(Pack<42>& A0, Pack<42>& A1, int gb4) {
    float srcK;
    if constexpr (K < 21) srcK = pget<K>(A0); else srcK = pget<K>(A1);
    float piv  = bperm(gb4 + 4 * (K < 21 ? K : K - 21), srcK);   // M[K][K] per group
    float invp = (piv > 1e-30f) ? 1.0f / piv : 0.0f;
    float t0   = invp * pget<K>(A0);     // 0 for already-eliminated columns
    float t1   = invp * pget<K>(A1);
    elim2_rows<K, K + 1>(A0, A1, t0, t1, gb4);
}
template<int... Ks> __device__ __forceinline__
void elim2_all(Pack<42>& A0, Pack<42>& A1, int gb4,
               std::integer_sequence<int, Ks...>) {
    ((elim2_step<Ks>(A0, A1, gb4)), ...);
}

template<int R> __device__ __forceinline__
void kdump2(Pack<42>& A1, float* Klg, int c10) {  // u in [11,21): col c10 of K
    if constexpr (R < DD + 10) {
        if constexpr (R >= DD)
            Klg[(R - DD) * 10 + c10] = -pget<R>(A1);
        kdump2<R + 1>(A1, Klg, c10);
    }
}

// ---- row-parallel 8x8 GJ (lane = (sub-system, row)), one pass per system ----
template<int L> __device__ __forceinline__
void tinit(Pack<12>& T, int row, int sys, const float* Kl, const float* zb) {
    if constexpr (L < 12) {
        float v;
        if constexpr (L < 8) {
            float kij = (row <= sys && L <= sys) ? Kl[row * 10 + L] : 0.0f;
            v = kij + ((row == L) ? 1.0f : 0.0f);
        } else if constexpr (L == 8)  v = (row <= sys) ? Kl[row * 10 + 8] : 0.0f;       // KUp
        else if constexpr (L == 9)    v = (row <= sys) ? zb[row * ZD + DD] : 0.0f;      // t_i
        else if constexpr (L == 10)   v = (row <= sys) ? Kl[row * 10 + 9] : 0.0f;       // KUq
        else                          v = (row <= sys) ? zb[row * ZD + DD + 1] : 0.0f;  // y_i
        pget<L>(T) = v;
        tinit<L + 1>(T, row, sys, Kl, zb);
    }
}
template<int K, int J> __device__ __forceinline__
void gjp_cols(Pack<12>& T, float f, int pb) {
    if constexpr (J < 12) {
        float pk = bperm(pb + 4 * K, pget<J>(T));   // pivot row K, col J
        pget<J>(T) = fmaf(-f, pk, pget<J>(T));
        gjp_cols<K, J + 1>(T, f, pb);
    }
}
template<int K> __device__ __forceinline__
void gjp_step(Pack<12>& T, int pb, int row, float& diag) {
    float pkK  = bperm(pb + 4 * K, pget<K>(T));     // M[K][K] of own sub-system
    float invp = (pkK > 1e-30f || pkK < -1e-30f) ? 1.0f / pkK : 0.0f;
    float f    = (row == K) ? 0.0f : pget<K>(T) * invp;
    gjp_cols<K, K + 1>(T, f, pb);
    if (row == K) diag = pget<K>(T);                // T[K][K] final after step K
}
template<int... Ks> __device__ __forceinline__
void gjp_all(Pack<12>& T, int pb, int row, float& diag,
             std::integer_sequence<int, Ks...>) {
    ((gjp_step<Ks>(T, pb, row, diag)), ...);
}

// ONE WAVE per 3 systems (ids id0..id0+2). Per-wave private LDS slices, no
// barriers (DS pipe is in-order per wave). Snapshot Sn[w] assembled from
// segment pieces; bperm-based dual-column elimination across 3 groups;
// then 3 sequential row-parallel GJ passes (8 sub-systems x 8 rows).
//   den = Stt0 - Kpp + sum_i (KpU_i - t_i)(s1_i - s2_i), s1=S^-1 KUp, s2=S^-1 t
//   num = Sty0 - Kpq + sum_i (KpU_i - t_i)(r1_i - r2_i), r1=S^-1 KUq, r2=S^-1 y
__global__ __launch_bounds__(64) void dml_solve(const float* __restrict__ xtys,
                                                const float* __restrict__ P,
                                                float* __restrict__ out) {
    const int lane = threadIdx.x;
    const int id0  = blockIdx.x * SPW3;        // 1280 blocks x 3 = 3840 systems

    __shared__ float snS[SPW3 * NE];
    __shared__ float zbS[SPW3 * WIN * ZD];
    __shared__ float KlS[SPW3 * 100];

    for (int q = 0; q < SPW3; ++q) {
        const int idq = id0 + q;
        const int w   = (idq % WACT) + 4;
        const int b   = idq / WACT;
        const int sg  = w >> 4;                // source segment
        const int kk  = w & 15;
        const float* pb_ = P + (size_t)b * SEG * PSTRIDE * NE;
        const float* src = xtys + ((size_t)b * NN + (size_t)w * WIN) * ZD;
        float* snq = snS + q * NE;
        float* zbq = zbS + q * (WIN * ZD);
        for (int u = lane; u < NE; u += 64) {
            float v = pb_[(size_t)(sg * PSTRIDE + kk) * NE + u];
            for (int g2 = 0; g2 < sg; ++g2)
                v += pb_[(size_t)(g2 * PSTRIDE + KWS) * NE + u];
            snq[u] = v;
        }
        for (int u = lane; u < WIN * ZD; u += 64) zbq[u] = src[u];
    }
    // no __syncthreads: single-wave WG, DS pipe in-order

    const int g    = (lane >= 2 * 21) ? 2 : (lane / 21);   // lane 63 -> dup of g2
    const int u    = lane - g * 21;                        // lane 63: u = 21
    const int c0   = u;
    const int c1   = u + 21;
    const int off0 = c0 * (ZD - 1) - (c0 * (c0 - 1)) / 2;  // eidx(c0, R) = off0 + R
    const int off1 = c1 * (ZD - 1) - (c1 * (c1 - 1)) / 2;
    const int gb4  = g * 21 * 4;                           // group base, bytes
    const float* snW = snS + g * NE;
    const float* zbW = zbS + g * (WIN * ZD);

    Pack<42> A0, A1;
    init2<0>(A0, A1, c0, c1, off0, off1, snW, zbW);

    elim2_all(A0, A1, gb4, std::make_integer_sequence<int, DD>{});

    if (u >= 11 && u < 21) kdump2<0>(A1, (float*)(KlS + g * 100), u - 11);
    // no barrier: kdump writes and GJ reads are same-wave, DS in-order

    const int sys = lane >> 3;                 // sub-system: n = 8w + sys
    const int row = lane & 7;
    const int pbB = (lane & ~7) << 2;          // byte base of own 8-lane group

    for (int q = 0; q < SPW3; ++q) {
        const int idq = id0 + q;
        const int w   = (idq % WACT) + 4;
        const int b   = idq / WACT;
        const float* Klq = KlS + q * 100;
        const float* zbq = zbS + q * (WIN * ZD);

        Pack<12> T;
        tinit<0>(T, row, sys, Klq, zbq);
        float diag = 1.0f;
        gjp_all(T, pbB, row, diag, std::make_integer_sequence<int, 8>{});

        float dinv = (diag > 1e-30f || diag < -1e-30f) ? 1.0f / diag : 0.0f;
        double s1 = (double)(pget<8>(T) * dinv);
        double s2 = (double)(pget<9>(T) * dinv);
        double r1 = (double)(pget<10>(T) * dinv);
        double r2 = (double)(pget<11>(T) * dinv);
        double gg = (double)Klq[80 + row] - (double)zbq[row * ZD + DD]; // KpU_i - t_i
        double cd = gg * (s1 - s2);
        double cn = gg * (r1 - r2);
#pragma unroll
        for (int m = 1; m < 8; m <<= 1) {
            cd += __shfl_xor(cd, m, 8);
            cn += __shfl_xor(cn, m, 8);
        }

        double Stt0 = (double)snS[q * NE + 592];
        double Sty0 = (double)snS[q * NE + 593];
        double den  = Stt0 - (double)Klq[88] + cd;  // Stt0 - Kpp + dterm
        double num  = Sty0 - (double)Klq[89] + cn;  // Sty0 - Kpq + nterm
        double val  = (den > 0.0) ? num / den : 0.0;
        if (!isfinite(val)) val = 0.0;
        if (row == 0) out[b * NN + w * WIN + sys] = (float)val;
    }
}

extern "C" void kernel_launch(void* const* d_in, const int* in_sizes, int n_in,
                              void* d_out, int out_size, void* d_ws, size_t ws_size,
                              hipStream_t stream) {
    const float* xtys = (const float*)d_in[0];
    float* out = (float*)d_out;
    float* P = (float*)d_ws;   // [BB][SEG][17][NE] fp32 = 10.36 MB

    hipLaunchKernelGGL(dml_gram, dim3(BB * SEG * CH), dim3(256), 0, stream, xtys, P, out);
    hipLaunchKernelGGL(dml_solve, dim3(BB * WACT / SPW3), dim3(64), 0, stream, xtys, P, out);
}